// Round 6
// baseline (1095.909 us; speedup 1.0000x reference)
//
#include <hip/hip_runtime.h>
#include <hip/hip_bf16.h>

#define N_NODES 100000
#define N_EDGES 1250000
#define HID 64
#define LDSS 72       // LDS row stride in bf16 elems: 64 + 8 pad (144 B rows)
#define NBK 1563      // fine buckets of 64 node-ids == GEMM blocks
#define NBKP 1568     // padded
#define NBLOCK 128    // edge-slice blocks for hist/scatter
#define EMB_BLOCKS 6250  // N_NODES*16/256 exactly

typedef __bf16 bf16x8 __attribute__((ext_vector_type(8)));
typedef float  f32x4  __attribute__((ext_vector_type(4)));

__device__ __forceinline__ float bflo(uint u) {   // low bf16 of packed uint -> f32
    union { unsigned int i; float f; } v; v.i = u << 16; return v.f;
}
__device__ __forceinline__ float bfhi(uint u) {   // high bf16 -> f32
    union { unsigned int i; float f; } v; v.i = u & 0xFFFF0000u; return v.f;
}
__device__ __forceinline__ ushort f2bf(float f) {
    union { float f; unsigned int i; } v; v.f = f;
    unsigned int x = v.i;
    return (ushort)((x + 0x7fffu + ((x >> 16) & 1u)) >> 16);  // RNE
}

// Fused prep: blocks [0,6250) embed-gather, [6250,6378) fine-bucket edge
// histogram (1563 buckets of 64 nodes), [6378,6383) weight convert.
__global__ __launch_bounds__(256) void prep(const int* __restrict__ x,
                                            const float* __restrict__ emb,
                                            ushort* __restrict__ h0,
                                            const int* __restrict__ dst,
                                            int* __restrict__ gh,
                                            const float* __restrict__ Wl1,
                                            const float* __restrict__ Wr1,
                                            const float* __restrict__ Wl2,
                                            const float* __restrict__ Wr2,
                                            const float* __restrict__ Wout,
                                            ushort* __restrict__ wbf) {
    const int b = blockIdx.x;
    const int tid = threadIdx.x;
    if (b < EMB_BLOCKS) {
        int t = b * 256 + tid;
        int row = t >> 4, c = t & 15;
        int idx = x[row];
        float4 v = ((const float4*)(emb + (size_t)idx * HID))[c];
        ushort4 w;
        w.x = f2bf(v.x); w.y = f2bf(v.y); w.z = f2bf(v.z); w.w = f2bf(v.w);
        ((ushort4*)(h0 + (size_t)row * HID))[c] = w;
    } else if (b < EMB_BLOCKS + NBLOCK) {
        __shared__ int hist[NBKP];
        const int bb = b - EMB_BLOCKS;
        for (int i = tid; i < NBKP; i += 256) hist[i] = 0;
        __syncthreads();
        const int4* d4 = (const int4*)dst;            // N_EDGES % 4 == 0
        for (int e = bb * 256 + tid; e < N_EDGES / 4; e += NBLOCK * 256) {
            int4 v = d4[e];
            atomicAdd(&hist[v.x >> 6], 1);
            atomicAdd(&hist[v.y >> 6], 1);
            atomicAdd(&hist[v.z >> 6], 1);
            atomicAdd(&hist[v.w >> 6], 1);
        }
        __syncthreads();
        for (int i = tid; i < NBKP; i += 256) gh[bb * NBKP + i] = hist[i];
    } else {
        const int wb = b - EMB_BLOCKS - NBLOCK;
        const float* W = (wb == 0) ? Wl1 : (wb == 1) ? Wr1 :
                         (wb == 2) ? Wl2 : (wb == 3) ? Wr2 : Wout;
        ushort* o = wbf + wb * 4096;
        for (int idx = tid; idx < 4096; idx += 256) {
            int k = idx >> 6, n = idx & 63;
            o[n * 64 + k] = f2bf(W[idx]);   // wbf[m][n*64+k] = bf16(W[k][n])
        }
    }
}

// Column prefix over the 128 per-slice counts of each bucket (in place);
// bucket totals to btot. 13 blocks x 128 threads, coalesced rows.
__global__ __launch_bounds__(128) void p2a(int* __restrict__ gh,
                                           int* __restrict__ btot) {
    int v = blockIdx.x * 128 + threadIdx.x;
    if (v >= NBK) return;
    int run = 0;
#pragma unroll 8
    for (int b = 0; b < NBLOCK; ++b) {
        int c = gh[b * NBKP + v];
        gh[b * NBKP + v] = run;
        run += c;
    }
    btot[v] = run;
}

// Exclusive scan of the 1563 bucket totals -> bstart. One block.
__global__ __launch_bounds__(256) void p2b(const int* __restrict__ btot,
                                           int* __restrict__ bstart) {
    __shared__ int wsum[4];
    const int t = threadIdx.x, lane = t & 63, wave = t >> 6;
    const int base = t * 7;                 // 256*7 = 1792 >= 1563
    int pre[7];
    int s = 0;
#pragma unroll
    for (int k = 0; k < 7; ++k) {
        int idx = base + k;
        int c = (idx < NBK) ? btot[idx] : 0;
        pre[k] = s;
        s += c;
    }
    int x = s;
#pragma unroll
    for (int d = 1; d < 64; d <<= 1) {
        int y = __shfl_up(x, d, 64);
        if (lane >= d) x += y;
    }
    if (lane == 63) wsum[wave] = x;
    __syncthreads();
    if (wave == 0) {
        int s2 = (lane < 4) ? wsum[lane] : 0;
#pragma unroll
        for (int d = 1; d < 4; d <<= 1) {
            int y = __shfl_up(s2, d, 64);
            if (lane >= d) s2 += y;
        }
        if (lane < 4) wsum[lane] = s2;
    }
    __syncthreads();
    int waveoff = (wave == 0) ? 0 : wsum[wave - 1];
    int excl = waveoff + (x - s);
#pragma unroll
    for (int k = 0; k < 7; ++k) {
        int idx = base + k;
        if (idx < NBK) bstart[idx] = excl + pre[k];
    }
    if (t == 0) bstart[NBK] = N_EDGES;
}

// Scatter edges into fine-bucket-sorted ebuf: payload = (dst&63)<<17 | src.
__global__ __launch_bounds__(256) void p3_scatter(const int* __restrict__ src,
                                                  const int* __restrict__ dst,
                                                  const int* __restrict__ gh,
                                                  const int* __restrict__ bstart,
                                                  uint* __restrict__ ebuf) {
    __shared__ int base[NBK];
    __shared__ int run[NBK];
    const int tid = threadIdx.x;
    for (int i = tid; i < NBK; i += 256) {
        base[i] = bstart[i] + gh[blockIdx.x * NBKP + i];
        run[i] = 0;
    }
    __syncthreads();
    const int4* s4 = (const int4*)src;
    const int4* d4 = (const int4*)dst;
    for (int e = blockIdx.x * 256 + tid; e < N_EDGES / 4; e += NBLOCK * 256) {
        int4 dv = d4[e];
        int4 sv = s4[e];
        int b0 = dv.x >> 6;
        int r0 = atomicAdd(&run[b0], 1);
        ebuf[base[b0] + r0] = ((uint)(dv.x & 63) << 17) | (uint)sv.x;
        int b1 = dv.y >> 6;
        int r1 = atomicAdd(&run[b1], 1);
        ebuf[base[b1] + r1] = ((uint)(dv.y & 63) << 17) | (uint)sv.y;
        int b2 = dv.z >> 6;
        int r2 = atomicAdd(&run[b2], 1);
        ebuf[base[b2] + r2] = ((uint)(dv.z & 63) << 17) | (uint)sv.z;
        int b3 = dv.w >> 6;
        int r3 = atomicAdd(&run[b3], 1);
        ebuf[base[b3] + r3] = ((uint)(dv.w & 63) << 17) | (uint)sv.w;
    }
}

// Fused layer, edge-parallel atomic aggregation + MFMA GEMM:
//  - block == fine bucket == 64 output nodes; its edges are one contiguous
//    UNSORTED slice of ebuf (no rowptr, no per-node CSR).
//  - aggregation: 8-lane group per edge; per 32-edge block-iteration each
//    lane does 1 independent dwordx4 gather + 8 ds_add_f32 into
//    sMean[64][65] (stride-65 -> random-dl bank spread ~2/bank = free).
//    NO serial chains: every iteration's loads are independent -> MLP by
//    construction, regardless of register allocator.
//  - one __syncthreads, then mean->bf16 into sA (rows wave-private for GEMM).
//  - weights + hin A-fragments read directly from global (L2-hot).
template <bool OUTPROJ>
__global__ __launch_bounds__(256, 4) void layer_fused(
    const int* __restrict__ bstart, const uint* __restrict__ ebuf,
    const ushort* __restrict__ hin,
    const ushort* __restrict__ wl_bf, const float* __restrict__ bl,
    const ushort* __restrict__ wr_bf, const float* __restrict__ alpha_p,
    const ushort* __restrict__ wo_bf, const float* __restrict__ bo,
    void* __restrict__ out_p) {
    __shared__ float sM[64][65];                       // 16640 B
    __shared__ int cnt[64];
    __shared__ __align__(16) ushort sA[64][LDSS];      // 9216 B

    const int tid = threadIdx.x;
    const int row0 = blockIdx.x * 64;
    const int wave = tid >> 6, lane = tid & 63;

    // ---- zero accumulators ----
    float* smf = &sM[0][0];
    for (int i = tid; i < 64 * 65; i += 256) smf[i] = 0.f;
    if (tid < 64) cnt[tid] = 0;
    __syncthreads();

    // ---- edge-parallel aggregation ----
    {
        const int estart = bstart[blockIdx.x];
        const int eend = bstart[blockIdx.x + 1];
        const int grp = tid >> 3, p = tid & 7;         // 32 edges / iteration
        const int nit = (eend - estart + 31) >> 5;
#pragma unroll 2
        for (int it = 0; it < nit; ++it) {
            int e = estart + it * 32 + grp;
            if (e < eend) {
                uint pk = ebuf[e];                     // 8-lane broadcast
                int dl = pk >> 17, s = pk & 0x1FFFF;
                uint4 w = *(const uint4*)&hin[(size_t)s * HID + p * 8];
                float* m = &sM[dl][p * 8];
                atomicAdd(m + 0, bflo(w.x)); atomicAdd(m + 1, bfhi(w.x));
                atomicAdd(m + 2, bflo(w.y)); atomicAdd(m + 3, bfhi(w.y));
                atomicAdd(m + 4, bflo(w.z)); atomicAdd(m + 5, bfhi(w.z));
                atomicAdd(m + 6, bflo(w.w)); atomicAdd(m + 7, bfhi(w.w));
                if (p == 0) atomicAdd(&cnt[dl], 1);
            }
        }
    }
    __syncthreads();

    // ---- mean -> bf16 sA (thread t: node t>>2, dims (t&3)*16..+15) ----
    {
        const int n = tid >> 2, q = tid & 3;
        int c = cnt[n];
        float inv = (c > 0) ? 1.0f / (float)c : 0.f;
        const float* m = &sM[n][q * 16];
        uint4 o0, o1;
        o0.x = (uint)f2bf(m[0] * inv)  | ((uint)f2bf(m[1] * inv) << 16);
        o0.y = (uint)f2bf(m[2] * inv)  | ((uint)f2bf(m[3] * inv) << 16);
        o0.z = (uint)f2bf(m[4] * inv)  | ((uint)f2bf(m[5] * inv) << 16);
        o0.w = (uint)f2bf(m[6] * inv)  | ((uint)f2bf(m[7] * inv) << 16);
        o1.x = (uint)f2bf(m[8] * inv)  | ((uint)f2bf(m[9] * inv) << 16);
        o1.y = (uint)f2bf(m[10] * inv) | ((uint)f2bf(m[11] * inv) << 16);
        o1.z = (uint)f2bf(m[12] * inv) | ((uint)f2bf(m[13] * inv) << 16);
        o1.w = (uint)f2bf(m[14] * inv) | ((uint)f2bf(m[15] * inv) << 16);
        *(uint4*)&sA[n][q * 16] = o0;
        *(uint4*)&sA[n][q * 16 + 8] = o1;
    }
    // no barrier: wave w wrote nodes 16w..16w+15 == the sA rows it reads below

    // ---- MFMA: wave w owns rows r0..r0+15; B-fragments straight from global
    const int quad = lane >> 4, lr = lane & 15;
    const int r0 = wave * 16;
    const int grow = row0 + r0 + lr;
    const float alpha = alpha_p[0];

    bf16x8 hf[2], af[2];
#pragma unroll
    for (int ks = 0; ks < 2; ++ks) {
        int k0 = ks * 32 + quad * 8;
        uint4 hv = {0, 0, 0, 0};
        if (grow < N_NODES) hv = *(const uint4*)&hin[(size_t)grow * HID + k0];
        hf[ks] = __builtin_bit_cast(bf16x8, hv);
        uint4 av = *(const uint4*)&sA[r0 + lr][k0];
        af[ks] = __builtin_bit_cast(bf16x8, av);
    }

    f32x4 acc[4];
#pragma unroll
    for (int nt = 0; nt < 4; ++nt) {
        f32x4 a = {0.f, 0.f, 0.f, 0.f};
#pragma unroll
        for (int ks = 0; ks < 2; ++ks) {
            int k0 = ks * 32 + quad * 8;
            bf16x8 wr = *(const bf16x8*)&wr_bf[(nt * 16 + lr) * 64 + k0];
            a = __builtin_amdgcn_mfma_f32_16x16x32_bf16(hf[ks], wr, a, 0, 0, 0);
            bf16x8 wl = *(const bf16x8*)&wl_bf[(nt * 16 + lr) * 64 + k0];
            a = __builtin_amdgcn_mfma_f32_16x16x32_bf16(af[ks], wl, a, 0, 0, 0);
        }
        acc[nt] = a;
    }

    if constexpr (!OUTPROJ) {
        // PReLU result -> sA (wave-private rows), then packed uint4 stores
#pragma unroll
        for (int nt = 0; nt < 4; ++nt) {
            int col = nt * 16 + lr;
            float bias = bl[col];
#pragma unroll
            for (int r = 0; r < 4; ++r) {
                int row = r0 + quad * 4 + r;  // C/D: col=lane&15, row=(lane>>4)*4+reg
                float v = acc[nt][r] + bias;
                v = (v >= 0.f) ? v : alpha * v;
                sA[row][col] = f2bf(v);
            }
        }
        ushort* outp = (ushort*)out_p;
        const int lrow = lane >> 3, lch = lane & 7;  // 8 rows x 8 chunks per pass
#pragma unroll
        for (int pass = 0; pass < 2; ++pass) {
            int row = r0 + pass * 8 + lrow;
            int gg2 = row0 + row;
            if (gg2 < N_NODES) {
                uint4 v4 = *(const uint4*)&sA[row][lch * 8];
                *(uint4*)&outp[(size_t)gg2 * HID + lch * 8] = v4;
            }
        }
    } else {
        // h2 (post-PReLU bf16) -> sA (wave-private rows), then @Wout + bout, f32
#pragma unroll
        for (int nt = 0; nt < 4; ++nt) {
            int col = nt * 16 + lr;
            float bias = bl[col];
#pragma unroll
            for (int r = 0; r < 4; ++r) {
                int row = r0 + quad * 4 + r;
                float v = acc[nt][r] + bias;
                v = (v >= 0.f) ? v : alpha * v;
                sA[row][col] = f2bf(v);
            }
        }
        bf16x8 h2f[2];
#pragma unroll
        for (int ks = 0; ks < 2; ++ks) {
            int k0 = ks * 32 + quad * 8;
            uint4 hv = *(const uint4*)&sA[r0 + lr][k0];
            h2f[ks] = __builtin_bit_cast(bf16x8, hv);
        }
        f32x4 acc2[4];
#pragma unroll
        for (int nt = 0; nt < 4; ++nt) {
            f32x4 a = {0.f, 0.f, 0.f, 0.f};
#pragma unroll
            for (int ks = 0; ks < 2; ++ks) {
                int k0 = ks * 32 + quad * 8;
                bf16x8 wo = *(const bf16x8*)&wo_bf[(nt * 16 + lr) * 64 + k0];
                a = __builtin_amdgcn_mfma_f32_16x16x32_bf16(h2f[ks], wo, a, 0, 0, 0);
            }
            acc2[nt] = a;
        }
        float* outp = (float*)out_p;
#pragma unroll
        for (int nt = 0; nt < 4; ++nt) {
            int col = nt * 16 + lr;
            float bias = bo[col];
#pragma unroll
            for (int r = 0; r < 4; ++r) {
                int row = r0 + quad * 4 + r;
                int gg2 = row0 + row;
                if (gg2 < N_NODES)
                    outp[(size_t)gg2 * HID + col] = acc2[nt][r] + bias;
            }
        }
    }
}

extern "C" void kernel_launch(void* const* d_in, const int* in_sizes, int n_in,
                              void* d_out, int out_size, void* d_ws, size_t ws_size,
                              hipStream_t stream) {
    const int*   x    = (const int*)d_in[0];
    const int*   src  = (const int*)d_in[1];
    const int*   dst  = src + N_EDGES;
    const float* emb  = (const float*)d_in[3];
    const float* Wl1  = (const float*)d_in[4];
    const float* bl1  = (const float*)d_in[5];
    const float* Wr1  = (const float*)d_in[6];
    const float* a1   = (const float*)d_in[7];
    const float* Wl2  = (const float*)d_in[8];
    const float* bl2  = (const float*)d_in[9];
    const float* Wr2  = (const float*)d_in[10];
    const float* a2   = (const float*)d_in[11];
    const float* Wout = (const float*)d_in[12];
    const float* bout = (const float*)d_in[13];

    char* ws = (char*)d_ws;
    int*    gh      = (int*)ws;                      // 128*1568*4 = 802,816
    int*    btot    = (int*)(ws + 802816);           // 6,272
    int*    bstart  = (int*)(ws + 809088);           // 6,272
    ushort* wbf     = (ushort*)(ws + 815360);        // 40,960
    uint*   ebuf    = (uint*)(ws + 856320);          // 5,000,000
    ushort* h0      = (ushort*)(ws + 5856320);       // 12.8 MB
    ushort* h1      = (ushort*)(ws + 18656320);      // 12.8 MB (end 31.5 MB)

    ushort* wl1b  = wbf;
    ushort* wr1b  = wbf + 4096;
    ushort* wl2b  = wbf + 8192;
    ushort* wr2b  = wbf + 12288;
    ushort* woutb = wbf + 16384;

    prep<<<EMB_BLOCKS + NBLOCK + 5, 256, 0, stream>>>(
        x, emb, h0, dst, gh, Wl1, Wr1, Wl2, Wr2, Wout, wbf);
    p2a<<<(NBK + 127) / 128, 128, 0, stream>>>(gh, btot);
    p2b<<<1, 256, 0, stream>>>(btot, bstart);
    p3_scatter<<<NBLOCK, 256, 0, stream>>>(src, dst, gh, bstart, ebuf);

    layer_fused<false><<<NBK, 256, 0, stream>>>(
        bstart, ebuf, h0, wl1b, bl1, wr1b, a1, wr1b, bl1, h1);
    layer_fused<true><<<NBK, 256, 0, stream>>>(
        bstart, ebuf, h1, wl2b, bl2, wr2b, a2, woutb, bout, d_out);
}

// Round 7
// 340.509 us; speedup vs baseline: 3.2184x; 3.2184x over previous
//
#include <hip/hip_runtime.h>
#include <hip/hip_bf16.h>

#define N_NODES 100000
#define N_EDGES 1250000
#define HID 64
#define LDSS 72       // LDS row stride in bf16 elems: 64 + 8 pad (144 B rows)
#define NB 196        // buckets of 512 node-ids: (100000+511)/512
#define NBLOCK 128    // edge-slice blocks for P1/P3
#define EMB_BLOCKS 6250  // N_NODES*16/256 exactly

typedef __bf16 bf16x8 __attribute__((ext_vector_type(8)));
typedef float  f32x4  __attribute__((ext_vector_type(4)));

__device__ __forceinline__ float bflo(uint u) {   // low bf16 of packed uint -> f32
    union { unsigned int i; float f; } v; v.i = u << 16; return v.f;
}
__device__ __forceinline__ float bfhi(uint u) {   // high bf16 -> f32
    union { unsigned int i; float f; } v; v.i = u & 0xFFFF0000u; return v.f;
}
__device__ __forceinline__ ushort f2bf(float f) {
    union { float f; unsigned int i; } v; v.f = f;
    unsigned int x = v.i;
    return (ushort)((x + 0x7fffu + ((x >> 16) & 1u)) >> 16);  // RNE
}

// Fused prep: blocks [0,6250) embed-gather, [6250,6378) edge histogram,
// [6378,6383) weight convert. All independent -> overlap on-chip.
__global__ __launch_bounds__(256) void prep(const int* __restrict__ x,
                                            const float* __restrict__ emb,
                                            ushort* __restrict__ h0,
                                            const int* __restrict__ dst,
                                            int* __restrict__ gh,
                                            const float* __restrict__ Wl1,
                                            const float* __restrict__ Wr1,
                                            const float* __restrict__ Wl2,
                                            const float* __restrict__ Wr2,
                                            const float* __restrict__ Wout,
                                            ushort* __restrict__ wbf) {
    const int b = blockIdx.x;
    const int tid = threadIdx.x;
    if (b < EMB_BLOCKS) {
        int t = b * 256 + tid;
        int row = t >> 4, c = t & 15;
        int idx = x[row];
        float4 v = ((const float4*)(emb + (size_t)idx * HID))[c];
        ushort4 w;
        w.x = f2bf(v.x); w.y = f2bf(v.y); w.z = f2bf(v.z); w.w = f2bf(v.w);
        ((ushort4*)(h0 + (size_t)row * HID))[c] = w;
    } else if (b < EMB_BLOCKS + NBLOCK) {
        __shared__ int hist[NB];
        const int bb = b - EMB_BLOCKS;
        for (int i = tid; i < NB; i += 256) hist[i] = 0;
        __syncthreads();
        const int4* d4 = (const int4*)dst;            // N_EDGES % 4 == 0
        for (int e = bb * 256 + tid; e < N_EDGES / 4; e += NBLOCK * 256) {
            int4 v = d4[e];
            atomicAdd(&hist[v.x >> 9], 1);
            atomicAdd(&hist[v.y >> 9], 1);
            atomicAdd(&hist[v.z >> 9], 1);
            atomicAdd(&hist[v.w >> 9], 1);
        }
        __syncthreads();
        for (int i = tid; i < NB; i += 256) gh[bb * NB + i] = hist[i];
    } else {
        const int wb = b - EMB_BLOCKS - NBLOCK;
        const float* W = (wb == 0) ? Wl1 : (wb == 1) ? Wr1 :
                         (wb == 2) ? Wl2 : (wb == 3) ? Wr2 : Wout;
        ushort* o = wbf + wb * 4096;
        for (int idx = tid; idx < 4096; idx += 256) {
            int k = idx >> 6, n = idx & 63;
            o[n * 64 + k] = f2bf(W[idx]);   // wbf[m][n*64+k] = bf16(W[k][n])
        }
    }
}

// Scatter into bucket-sorted ebuf. gh holds RAW per-(block,bucket) counts;
// each block recomputes the column-prefix + 196-bucket scan itself (~2 us).
// Block 0 publishes bstart for p4.
__global__ __launch_bounds__(256) void p3_scatter(const int* __restrict__ src,
                                                  const int* __restrict__ dst,
                                                  const int* __restrict__ gh,
                                                  int* __restrict__ bstart,
                                                  uint* __restrict__ ebuf) {
    __shared__ int base[NB];
    __shared__ int run[NB];
    __shared__ int wsum[4];
    const int tid = threadIdx.x, lane = tid & 63, wave = tid >> 6;
    int myTot = 0, myPre = 0;
    if (tid < NB) {
#pragma unroll 8
        for (int b = 0; b < NBLOCK; ++b) {
            int c = gh[b * NB + tid];
            if (b == (int)blockIdx.x) myPre = myTot;
            myTot += c;
        }
    }
    int x = myTot;
#pragma unroll
    for (int d = 1; d < 64; d <<= 1) {
        int y = __shfl_up(x, d, 64);
        if (lane >= d) x += y;
    }
    if (lane == 63) wsum[wave] = x;
    __syncthreads();
    if (wave == 0) {
        int s = (lane < 4) ? wsum[lane] : 0;
#pragma unroll
        for (int d = 1; d < 4; d <<= 1) {
            int y = __shfl_up(s, d, 64);
            if (lane >= d) s += y;
        }
        if (lane < 4) wsum[lane] = s;
    }
    __syncthreads();
    int waveoff = (wave == 0) ? 0 : wsum[wave - 1];
    int excl = waveoff + (x - myTot);
    if (tid < NB) {
        base[tid] = excl + myPre;
        run[tid] = 0;
        if (blockIdx.x == 0) bstart[tid] = excl;
    }
    if (blockIdx.x == 0 && tid == 0) bstart[NB] = N_EDGES;
    __syncthreads();
    const int4* s4 = (const int4*)src;
    const int4* d4 = (const int4*)dst;
    for (int e = blockIdx.x * 256 + tid; e < N_EDGES / 4; e += NBLOCK * 256) {
        int4 dv = d4[e];
        int4 sv = s4[e];
        int b0 = dv.x >> 9;
        int r0 = atomicAdd(&run[b0], 1);
        ebuf[base[b0] + r0] = ((uint)(dv.x & 511) << 17) | (uint)sv.x;
        int b1 = dv.y >> 9;
        int r1 = atomicAdd(&run[b1], 1);
        ebuf[base[b1] + r1] = ((uint)(dv.y & 511) << 17) | (uint)sv.y;
        int b2 = dv.z >> 9;
        int r2 = atomicAdd(&run[b2], 1);
        ebuf[base[b2] + r2] = ((uint)(dv.z & 511) << 17) | (uint)sv.z;
        int b3 = dv.w >> 9;
        int r3 = atomicAdd(&run[b3], 1);
        ebuf[base[b3] + r3] = ((uint)(dv.w & 511) << 17) | (uint)sv.w;
    }
}

__global__ __launch_bounds__(256) void p4_csr(const uint* __restrict__ ebuf,
                                              const int* __restrict__ bstart,
                                              int* __restrict__ rowptr,
                                              int* __restrict__ csr_src) {
    __shared__ int hist[512], hoff[512], run[512];
    __shared__ int wsum[4];
    const int v = blockIdx.x;
    const int tid = threadIdx.x, lane = tid & 63, wave = tid >> 6;
    const int node0 = v << 9;
    const int nn = min(512, N_NODES - node0);
    const int beg = bstart[v], end = bstart[v + 1];

    for (int i = tid; i < 512; i += 256) { hist[i] = 0; run[i] = 0; }
    __syncthreads();
    for (int e = beg + tid; e < end; e += 256)
        atomicAdd(&hist[ebuf[e] >> 17], 1);
    __syncthreads();
    int h0 = hist[2 * tid], h1 = hist[2 * tid + 1];
    int s = h0 + h1;
    int x = s;
#pragma unroll
    for (int d = 1; d < 64; d <<= 1) {
        int y = __shfl_up(x, d, 64);
        if (lane >= d) x += y;
    }
    if (lane == 63) wsum[wave] = x;
    __syncthreads();
    if (wave == 0) {
        int s2 = (lane < 4) ? wsum[lane] : 0;
#pragma unroll
        for (int d = 1; d < 4; d <<= 1) {
            int y = __shfl_up(s2, d, 64);
            if (lane >= d) s2 += y;
        }
        if (lane < 4) wsum[lane] = s2;
    }
    __syncthreads();
    int waveoff = (wave == 0) ? 0 : wsum[wave - 1];
    int excl = waveoff + (x - s);
    hoff[2 * tid] = excl;
    hoff[2 * tid + 1] = excl + h0;
    __syncthreads();
    for (int j = tid; j < nn; j += 256) rowptr[node0 + j] = beg + hoff[j];
    if (v == NB - 1 && tid == 0) rowptr[N_NODES] = N_EDGES;
    for (int e = beg + tid; e < end; e += 256) {
        uint p = ebuf[e];
        int dl = p >> 17;
        int r = atomicAdd(&run[dl], 1);
        csr_src[beg + hoff[dl] + r] = (int)(p & 0x1FFFFu);
    }
}

#define ACCUM(wa, wb)                                                      \
    a0 += bflo(wa.x); a1 += bfhi(wa.x); a2 += bflo(wa.y); a3 += bfhi(wa.y); \
    a4 += bflo(wa.z); a5 += bfhi(wa.z); a6 += bflo(wa.w); a7 += bfhi(wa.w); \
    a8 += bflo(wb.x); a9 += bfhi(wb.x); a10 += bflo(wb.y); a11 += bfhi(wb.y); \
    a12 += bflo(wb.z); a13 += bfhi(wb.z); a14 += bflo(wb.w); a15 += bfhi(wb.w);

#define GATHER(j)                                                          \
    const uint4* p##j = (const uint4*)&hin[(size_t)s##j * HID + q * 16];   \
    uint4 A##j = p##j[0], B##j = p##j[1];

// Fused layer, wave-autonomous, 2-wave blocks for occupancy + balance:
//  - 128-thread blocks, 32 nodes each -> 3125 blocks = 12.2 blocks/CU,
//    24 waves/CU grid cap; 1-wave (16-node) balance quantum kills the
//    64-node convoy tail that held occupancy at 35%.
//  - aggregation: 4 lanes/node; batch-8 gather with NEXT-batch index
//    prefetch issued before the current batch's accumulation (removes the
//    idx-load latency from the serial chain).
//  - weights + hin A-fragments read directly from global (L2-hot).
//  - only LDS: sA[32][72]; rows written+read by the SAME wave -> ZERO
//    __syncthreads.
template <bool OUTPROJ>
__global__ __launch_bounds__(128, 6) void layer_fused(
    const int* __restrict__ rowptr, const int* __restrict__ csr_src,
    const ushort* __restrict__ hin,
    const ushort* __restrict__ wl_bf, const float* __restrict__ bl,
    const ushort* __restrict__ wr_bf, const float* __restrict__ alpha_p,
    const ushort* __restrict__ wo_bf, const float* __restrict__ bo,
    void* __restrict__ out_p) {
    __shared__ __align__(16) ushort sA[32][LDSS];      // 4608 B

    const int tid = threadIdx.x;
    const int row0 = blockIdx.x * 32;
    const int wave = tid >> 6, lane = tid & 63;

    // ---- aggregation: group g (4 lanes) owns node row0+g; lane q covers dims
    // q*16..q*16+15 (two uint4 per neighbor)
    const int g = tid >> 2, q = tid & 3;
    {
        int node = row0 + g;
        uint4 o0 = {0, 0, 0, 0}, o1 = {0, 0, 0, 0};
        if (node < N_NODES) {
            int beg = rowptr[node], end = rowptr[node + 1];
            float a0 = 0.f, a1 = 0.f, a2 = 0.f, a3 = 0.f;
            float a4 = 0.f, a5 = 0.f, a6 = 0.f, a7 = 0.f;
            float a8 = 0.f, a9 = 0.f, a10 = 0.f, a11 = 0.f;
            float a12 = 0.f, a13 = 0.f, a14 = 0.f, a15 = 0.f;
            int i = beg;
            if (i + 8 <= end) {
                int s0 = csr_src[i + 0], s1 = csr_src[i + 1];
                int s2 = csr_src[i + 2], s3 = csr_src[i + 3];
                int s4 = csr_src[i + 4], s5 = csr_src[i + 5];
                int s6 = csr_src[i + 6], s7 = csr_src[i + 7];
                for (;;) {
                    GATHER(0) GATHER(1) GATHER(2) GATHER(3)
                    GATHER(4) GATHER(5) GATHER(6) GATHER(7)
                    const int ni = i + 8;
                    const bool more = (ni + 8 <= end);
                    int t0 = 0, t1 = 0, t2 = 0, t3 = 0;
                    int t4 = 0, t5 = 0, t6 = 0, t7 = 0;
                    if (more) {          // prefetch next batch's indices now
                        t0 = csr_src[ni + 0]; t1 = csr_src[ni + 1];
                        t2 = csr_src[ni + 2]; t3 = csr_src[ni + 3];
                        t4 = csr_src[ni + 4]; t5 = csr_src[ni + 5];
                        t6 = csr_src[ni + 6]; t7 = csr_src[ni + 7];
                    }
                    ACCUM(A0, B0) ACCUM(A1, B1) ACCUM(A2, B2) ACCUM(A3, B3)
                    ACCUM(A4, B4) ACCUM(A5, B5) ACCUM(A6, B6) ACCUM(A7, B7)
                    i = ni;
                    if (!more) break;
                    s0 = t0; s1 = t1; s2 = t2; s3 = t3;
                    s4 = t4; s5 = t5; s6 = t6; s7 = t7;
                }
            }
            if (i < end) {   // masked batch-8 tail: clamp idx, zero invalid slots
                const int e1 = end - 1;
                int s0 = csr_src[i + 0];
                int s1 = csr_src[(i + 1 <= e1) ? i + 1 : e1];
                int s2 = csr_src[(i + 2 <= e1) ? i + 2 : e1];
                int s3 = csr_src[(i + 3 <= e1) ? i + 3 : e1];
                int s4 = csr_src[(i + 4 <= e1) ? i + 4 : e1];
                int s5 = csr_src[(i + 5 <= e1) ? i + 5 : e1];
                int s6 = csr_src[(i + 6 <= e1) ? i + 6 : e1];
                int s7 = csr_src[(i + 7 <= e1) ? i + 7 : e1];
                GATHER(0) GATHER(1) GATHER(2) GATHER(3)
                GATHER(4) GATHER(5) GATHER(6) GATHER(7)
                const uint4 z = {0, 0, 0, 0};
                if (i + 1 > e1) { A1 = z; B1 = z; }
                if (i + 2 > e1) { A2 = z; B2 = z; }
                if (i + 3 > e1) { A3 = z; B3 = z; }
                if (i + 4 > e1) { A4 = z; B4 = z; }
                if (i + 5 > e1) { A5 = z; B5 = z; }
                if (i + 6 > e1) { A6 = z; B6 = z; }
                if (i + 7 > e1) { A7 = z; B7 = z; }
                ACCUM(A0, B0) ACCUM(A1, B1) ACCUM(A2, B2) ACCUM(A3, B3)
                ACCUM(A4, B4) ACCUM(A5, B5) ACCUM(A6, B6) ACCUM(A7, B7)
            }
            float inv = (end > beg) ? 1.0f / (float)(end - beg) : 0.f;
            o0.x = (uint)f2bf(a0 * inv)  | ((uint)f2bf(a1 * inv) << 16);
            o0.y = (uint)f2bf(a2 * inv)  | ((uint)f2bf(a3 * inv) << 16);
            o0.z = (uint)f2bf(a4 * inv)  | ((uint)f2bf(a5 * inv) << 16);
            o0.w = (uint)f2bf(a6 * inv)  | ((uint)f2bf(a7 * inv) << 16);
            o1.x = (uint)f2bf(a8 * inv)  | ((uint)f2bf(a9 * inv) << 16);
            o1.y = (uint)f2bf(a10 * inv) | ((uint)f2bf(a11 * inv) << 16);
            o1.z = (uint)f2bf(a12 * inv) | ((uint)f2bf(a13 * inv) << 16);
            o1.w = (uint)f2bf(a14 * inv) | ((uint)f2bf(a15 * inv) << 16);
        }
        *(uint4*)&sA[g][q * 16] = o0;
        *(uint4*)&sA[g][q * 16 + 8] = o1;
    }
    // no barrier: sA rows are wave-private (wave w wrote rows 16w..16w+15)

    // ---- MFMA: wave w owns rows r0..r0+15; B-fragments straight from global
    const int quad = lane >> 4, lr = lane & 15;
    const int r0 = wave * 16;
    const int grow = row0 + r0 + lr;
    const float alpha = alpha_p[0];

    bf16x8 hf[2], af[2];
#pragma unroll
    for (int ks = 0; ks < 2; ++ks) {
        int k0 = ks * 32 + quad * 8;
        uint4 hv = {0, 0, 0, 0};
        if (grow < N_NODES) hv = *(const uint4*)&hin[(size_t)grow * HID + k0];
        hf[ks] = __builtin_bit_cast(bf16x8, hv);
        uint4 av = *(const uint4*)&sA[r0 + lr][k0];
        af[ks] = __builtin_bit_cast(bf16x8, av);
    }

    f32x4 acc[4];
#pragma unroll
    for (int nt = 0; nt < 4; ++nt) {
        f32x4 a = {0.f, 0.f, 0.f, 0.f};
#pragma unroll
        for (int ks = 0; ks < 2; ++ks) {
            int k0 = ks * 32 + quad * 8;
            bf16x8 wr = *(const bf16x8*)&wr_bf[(nt * 16 + lr) * 64 + k0];
            a = __builtin_amdgcn_mfma_f32_16x16x32_bf16(hf[ks], wr, a, 0, 0, 0);
            bf16x8 wl = *(const bf16x8*)&wl_bf[(nt * 16 + lr) * 64 + k0];
            a = __builtin_amdgcn_mfma_f32_16x16x32_bf16(af[ks], wl, a, 0, 0, 0);
        }
        acc[nt] = a;
    }

    if constexpr (!OUTPROJ) {
        // PReLU result -> sA (wave-private rows), then packed uint4 stores
#pragma unroll
        for (int nt = 0; nt < 4; ++nt) {
            int col = nt * 16 + lr;
            float bias = bl[col];
#pragma unroll
            for (int r = 0; r < 4; ++r) {
                int row = r0 + quad * 4 + r;  // C/D: col=lane&15, row=(lane>>4)*4+reg
                float v = acc[nt][r] + bias;
                v = (v >= 0.f) ? v : alpha * v;
                sA[row][col] = f2bf(v);
            }
        }
        ushort* outp = (ushort*)out_p;
        const int lrow = lane >> 3, lch = lane & 7;  // 8 rows x 8 chunks per pass
#pragma unroll
        for (int pass = 0; pass < 2; ++pass) {
            int row = r0 + pass * 8 + lrow;
            int gg2 = row0 + row;
            if (gg2 < N_NODES) {
                uint4 v4 = *(const uint4*)&sA[row][lch * 8];
                *(uint4*)&outp[(size_t)gg2 * HID + lch * 8] = v4;
            }
        }
    } else {
        // h2 (post-PReLU bf16) -> sA (wave-private rows), then @Wout + bout, f32
#pragma unroll
        for (int nt = 0; nt < 4; ++nt) {
            int col = nt * 16 + lr;
            float bias = bl[col];
#pragma unroll
            for (int r = 0; r < 4; ++r) {
                int row = r0 + quad * 4 + r;
                float v = acc[nt][r] + bias;
                v = (v >= 0.f) ? v : alpha * v;
                sA[row][col] = f2bf(v);
            }
        }
        bf16x8 h2f[2];
#pragma unroll
        for (int ks = 0; ks < 2; ++ks) {
            int k0 = ks * 32 + quad * 8;
            uint4 hv = *(const uint4*)&sA[r0 + lr][k0];
            h2f[ks] = __builtin_bit_cast(bf16x8, hv);
        }
        f32x4 acc2[4];
#pragma unroll
        for (int nt = 0; nt < 4; ++nt) {
            f32x4 a = {0.f, 0.f, 0.f, 0.f};
#pragma unroll
            for (int ks = 0; ks < 2; ++ks) {
                int k0 = ks * 32 + quad * 8;
                bf16x8 wo = *(const bf16x8*)&wo_bf[(nt * 16 + lr) * 64 + k0];
                a = __builtin_amdgcn_mfma_f32_16x16x32_bf16(h2f[ks], wo, a, 0, 0, 0);
            }
            acc2[nt] = a;
        }
        float* outp = (float*)out_p;
#pragma unroll
        for (int nt = 0; nt < 4; ++nt) {
            int col = nt * 16 + lr;
            float bias = bo[col];
#pragma unroll
            for (int r = 0; r < 4; ++r) {
                int row = r0 + quad * 4 + r;
                int gg2 = row0 + row;
                if (gg2 < N_NODES)
                    outp[(size_t)gg2 * HID + col] = acc2[nt][r] + bias;
            }
        }
    }
}

extern "C" void kernel_launch(void* const* d_in, const int* in_sizes, int n_in,
                              void* d_out, int out_size, void* d_ws, size_t ws_size,
                              hipStream_t stream) {
    const int*   x    = (const int*)d_in[0];
    const int*   src  = (const int*)d_in[1];
    const int*   dst  = src + N_EDGES;
    const float* emb  = (const float*)d_in[3];
    const float* Wl1  = (const float*)d_in[4];
    const float* bl1  = (const float*)d_in[5];
    const float* Wr1  = (const float*)d_in[6];
    const float* a1   = (const float*)d_in[7];
    const float* Wl2  = (const float*)d_in[8];
    const float* bl2  = (const float*)d_in[9];
    const float* Wr2  = (const float*)d_in[10];
    const float* a2   = (const float*)d_in[11];
    const float* Wout = (const float*)d_in[12];
    const float* bout = (const float*)d_in[13];

    char* ws = (char*)d_ws;
    int*    gh      = (int*)ws;                      // 100,352 (pad 100,416)
    int*    bstart  = (int*)(ws + 101248);           // 832
    int*    rowptr  = (int*)(ws + 102080);           // 400,064
    ushort* wbf     = (ushort*)(ws + 502144);        // 40,960
    uint*   ebuf    = (uint*)(ws + 543104);          // 5,000,000
    int*    csr_src = (int*)(ws + 5543104);          // 5,000,000
    ushort* h0      = (ushort*)(ws + 10543104);      // 12.8 MB
    ushort* h1      = (ushort*)(ws + 23343104);      // 12.8 MB

    ushort* wl1b  = wbf;
    ushort* wr1b  = wbf + 4096;
    ushort* wl2b  = wbf + 8192;
    ushort* wr2b  = wbf + 12288;
    ushort* woutb = wbf + 16384;

    const int layer_blocks = N_NODES / 32;           // 3125 (exact)

    prep<<<EMB_BLOCKS + NBLOCK + 5, 256, 0, stream>>>(
        x, emb, h0, dst, gh, Wl1, Wr1, Wl2, Wr2, Wout, wbf);
    p3_scatter<<<NBLOCK, 256, 0, stream>>>(src, dst, gh, bstart, ebuf);
    p4_csr<<<NB, 256, 0, stream>>>(ebuf, bstart, rowptr, csr_src);

    layer_fused<false><<<layer_blocks, 128, 0, stream>>>(
        rowptr, csr_src, h0, wl1b, bl1, wr1b, a1, wr1b, bl1, h1);
    layer_fused<true><<<layer_blocks, 128, 0, stream>>>(
        rowptr, csr_src, h1, wl2b, bl2, wr2b, a2, woutb, bout, d_out);
}

// Round 8
// 234.927 us; speedup vs baseline: 4.6649x; 1.4494x over previous
//
#include <hip/hip_runtime.h>
#include <hip/hip_bf16.h>

#define N_NODES 100000
#define N_EDGES 1250000
#define HID 64
#define LDSS 72       // LDS row stride in bf16 elems: 64 + 8 pad (144 B rows)
#define NB 196        // buckets of 512 node-ids: (100000+511)/512
#define NBLOCK 128    // edge-slice blocks for P1/P3
#define EMB_BLOCKS 6250  // N_NODES*16/256 exactly

typedef __bf16 bf16x8 __attribute__((ext_vector_type(8)));
typedef float  f32x4  __attribute__((ext_vector_type(4)));

__device__ __forceinline__ float bflo(uint u) {   // low bf16 of packed uint -> f32
    union { unsigned int i; float f; } v; v.i = u << 16; return v.f;
}
__device__ __forceinline__ float bfhi(uint u) {   // high bf16 -> f32
    union { unsigned int i; float f; } v; v.i = u & 0xFFFF0000u; return v.f;
}
__device__ __forceinline__ ushort f2bf(float f) {
    union { float f; unsigned int i; } v; v.f = f;
    unsigned int x = v.i;
    return (ushort)((x + 0x7fffu + ((x >> 16) & 1u)) >> 16);  // RNE
}

// Fused prep: blocks [0,6250) embed-gather, [6250,6378) edge histogram,
// [6378,6383) weight convert. All independent -> overlap on-chip.
__global__ __launch_bounds__(256) void prep(const int* __restrict__ x,
                                            const float* __restrict__ emb,
                                            ushort* __restrict__ h0,
                                            const int* __restrict__ dst,
                                            int* __restrict__ gh,
                                            const float* __restrict__ Wl1,
                                            const float* __restrict__ Wr1,
                                            const float* __restrict__ Wl2,
                                            const float* __restrict__ Wr2,
                                            const float* __restrict__ Wout,
                                            ushort* __restrict__ wbf) {
    const int b = blockIdx.x;
    const int tid = threadIdx.x;
    if (b < EMB_BLOCKS) {
        int t = b * 256 + tid;
        int row = t >> 4, c = t & 15;
        int idx = x[row];
        float4 v = ((const float4*)(emb + (size_t)idx * HID))[c];
        ushort4 w;
        w.x = f2bf(v.x); w.y = f2bf(v.y); w.z = f2bf(v.z); w.w = f2bf(v.w);
        ((ushort4*)(h0 + (size_t)row * HID))[c] = w;
    } else if (b < EMB_BLOCKS + NBLOCK) {
        __shared__ int hist[NB];
        const int bb = b - EMB_BLOCKS;
        for (int i = tid; i < NB; i += 256) hist[i] = 0;
        __syncthreads();
        const int4* d4 = (const int4*)dst;            // N_EDGES % 4 == 0
        for (int e = bb * 256 + tid; e < N_EDGES / 4; e += NBLOCK * 256) {
            int4 v = d4[e];
            atomicAdd(&hist[v.x >> 9], 1);
            atomicAdd(&hist[v.y >> 9], 1);
            atomicAdd(&hist[v.z >> 9], 1);
            atomicAdd(&hist[v.w >> 9], 1);
        }
        __syncthreads();
        for (int i = tid; i < NB; i += 256) gh[bb * NB + i] = hist[i];
    } else {
        const int wb = b - EMB_BLOCKS - NBLOCK;
        const float* W = (wb == 0) ? Wl1 : (wb == 1) ? Wr1 :
                         (wb == 2) ? Wl2 : (wb == 3) ? Wr2 : Wout;
        ushort* o = wbf + wb * 4096;
        for (int idx = tid; idx < 4096; idx += 256) {
            int k = idx >> 6, n = idx & 63;
            o[n * 64 + k] = f2bf(W[idx]);   // wbf[m][n*64+k] = bf16(W[k][n])
        }
    }
}

// Scatter into bucket-sorted ebuf. gh holds RAW per-(block,bucket) counts;
// each block recomputes the column-prefix + 196-bucket scan itself (~2 us).
// Block 0 publishes bstart for p4.
__global__ __launch_bounds__(256) void p3_scatter(const int* __restrict__ src,
                                                  const int* __restrict__ dst,
                                                  const int* __restrict__ gh,
                                                  int* __restrict__ bstart,
                                                  uint* __restrict__ ebuf) {
    __shared__ int base[NB];
    __shared__ int run[NB];
    __shared__ int wsum[4];
    const int tid = threadIdx.x, lane = tid & 63, wave = tid >> 6;
    int myTot = 0, myPre = 0;
    if (tid < NB) {
#pragma unroll 8
        for (int b = 0; b < NBLOCK; ++b) {
            int c = gh[b * NB + tid];
            if (b == (int)blockIdx.x) myPre = myTot;
            myTot += c;
        }
    }
    int x = myTot;
#pragma unroll
    for (int d = 1; d < 64; d <<= 1) {
        int y = __shfl_up(x, d, 64);
        if (lane >= d) x += y;
    }
    if (lane == 63) wsum[wave] = x;
    __syncthreads();
    if (wave == 0) {
        int s = (lane < 4) ? wsum[lane] : 0;
#pragma unroll
        for (int d = 1; d < 4; d <<= 1) {
            int y = __shfl_up(s, d, 64);
            if (lane >= d) s += y;
        }
        if (lane < 4) wsum[lane] = s;
    }
    __syncthreads();
    int waveoff = (wave == 0) ? 0 : wsum[wave - 1];
    int excl = waveoff + (x - myTot);
    if (tid < NB) {
        base[tid] = excl + myPre;
        run[tid] = 0;
        if (blockIdx.x == 0) bstart[tid] = excl;
    }
    if (blockIdx.x == 0 && tid == 0) bstart[NB] = N_EDGES;
    __syncthreads();
    const int4* s4 = (const int4*)src;
    const int4* d4 = (const int4*)dst;
    for (int e = blockIdx.x * 256 + tid; e < N_EDGES / 4; e += NBLOCK * 256) {
        int4 dv = d4[e];
        int4 sv = s4[e];
        int b0 = dv.x >> 9;
        int r0 = atomicAdd(&run[b0], 1);
        ebuf[base[b0] + r0] = ((uint)(dv.x & 511) << 17) | (uint)sv.x;
        int b1 = dv.y >> 9;
        int r1 = atomicAdd(&run[b1], 1);
        ebuf[base[b1] + r1] = ((uint)(dv.y & 511) << 17) | (uint)sv.y;
        int b2 = dv.z >> 9;
        int r2 = atomicAdd(&run[b2], 1);
        ebuf[base[b2] + r2] = ((uint)(dv.z & 511) << 17) | (uint)sv.z;
        int b3 = dv.w >> 9;
        int r3 = atomicAdd(&run[b3], 1);
        ebuf[base[b3] + r3] = ((uint)(dv.w & 511) << 17) | (uint)sv.w;
    }
}

__global__ __launch_bounds__(256) void p4_csr(const uint* __restrict__ ebuf,
                                              const int* __restrict__ bstart,
                                              int* __restrict__ rowptr,
                                              int* __restrict__ csr_src) {
    __shared__ int hist[512], hoff[512], run[512];
    __shared__ int wsum[4];
    const int v = blockIdx.x;
    const int tid = threadIdx.x, lane = tid & 63, wave = tid >> 6;
    const int node0 = v << 9;
    const int nn = min(512, N_NODES - node0);
    const int beg = bstart[v], end = bstart[v + 1];

    for (int i = tid; i < 512; i += 256) { hist[i] = 0; run[i] = 0; }
    __syncthreads();
    for (int e = beg + tid; e < end; e += 256)
        atomicAdd(&hist[ebuf[e] >> 17], 1);
    __syncthreads();
    int h0 = hist[2 * tid], h1 = hist[2 * tid + 1];
    int s = h0 + h1;
    int x = s;
#pragma unroll
    for (int d = 1; d < 64; d <<= 1) {
        int y = __shfl_up(x, d, 64);
        if (lane >= d) x += y;
    }
    if (lane == 63) wsum[wave] = x;
    __syncthreads();
    if (wave == 0) {
        int s2 = (lane < 4) ? wsum[lane] : 0;
#pragma unroll
        for (int d = 1; d < 4; d <<= 1) {
            int y = __shfl_up(s2, d, 64);
            if (lane >= d) s2 += y;
        }
        if (lane < 4) wsum[lane] = s2;
    }
    __syncthreads();
    int waveoff = (wave == 0) ? 0 : wsum[wave - 1];
    int excl = waveoff + (x - s);
    hoff[2 * tid] = excl;
    hoff[2 * tid + 1] = excl + h0;
    __syncthreads();
    for (int j = tid; j < nn; j += 256) rowptr[node0 + j] = beg + hoff[j];
    if (v == NB - 1 && tid == 0) rowptr[N_NODES] = N_EDGES;
    for (int e = beg + tid; e < end; e += 256) {
        uint p = ebuf[e];
        int dl = p >> 17;
        int r = atomicAdd(&run[dl], 1);
        csr_src[beg + hoff[dl] + r] = (int)(p & 0x1FFFFu);
    }
}

#define ACCUM(wa, wb)                                                      \
    a0 += bflo(wa.x); a1 += bfhi(wa.x); a2 += bflo(wa.y); a3 += bfhi(wa.y); \
    a4 += bflo(wa.z); a5 += bfhi(wa.z); a6 += bflo(wa.w); a7 += bfhi(wa.w); \
    a8 += bflo(wb.x); a9 += bfhi(wb.x); a10 += bflo(wb.y); a11 += bfhi(wb.y); \
    a12 += bflo(wb.z); a13 += bfhi(wb.z); a14 += bflo(wb.w); a15 += bfhi(wb.w);

#define GATHER(j)                                                          \
    const uint4* p##j = (const uint4*)&hin[(size_t)s##j * HID + q * 16];   \
    uint4 A##j = p##j[0], B##j = p##j[1];

// Fused layer: r3's proven inner loop (batch-8, NO index prefetch -> 48 VGPR,
// no spill) in 2-wave 32-node blocks for occupancy + tail balance:
//  - 3125 blocks = 12.2 blocks/CU, 24.4 waves/CU grid budget (vs 6 blocks/CU
//    at 64-node blocks, which convoyed on the slowest 16-node wave).
//  - launch_bounds(128,4): VGPR cap 128 >> 48 actual -> zero spill risk
//    (r7's prefetch variant spilled: FETCH/WRITE ballooned to 162/162 MB).
//  - weights + hin A-fragments read directly from global (L2-hot).
//  - only LDS: sA[32][72]; rows written+read by the SAME wave -> ZERO
//    __syncthreads.
template <bool OUTPROJ>
__global__ __launch_bounds__(128, 4) void layer_fused(
    const int* __restrict__ rowptr, const int* __restrict__ csr_src,
    const ushort* __restrict__ hin,
    const ushort* __restrict__ wl_bf, const float* __restrict__ bl,
    const ushort* __restrict__ wr_bf, const float* __restrict__ alpha_p,
    const ushort* __restrict__ wo_bf, const float* __restrict__ bo,
    void* __restrict__ out_p) {
    __shared__ __align__(16) ushort sA[32][LDSS];      // 4608 B

    const int tid = threadIdx.x;
    const int row0 = blockIdx.x * 32;
    const int wave = tid >> 6, lane = tid & 63;

    // ---- aggregation: group g (4 lanes) owns node row0+g; lane q covers dims
    // q*16..q*16+15 (two uint4 per neighbor)
    const int g = tid >> 2, q = tid & 3;
    {
        int node = row0 + g;
        uint4 o0 = {0, 0, 0, 0}, o1 = {0, 0, 0, 0};
        if (node < N_NODES) {
            int beg = rowptr[node], end = rowptr[node + 1];
            float a0 = 0.f, a1 = 0.f, a2 = 0.f, a3 = 0.f;
            float a4 = 0.f, a5 = 0.f, a6 = 0.f, a7 = 0.f;
            float a8 = 0.f, a9 = 0.f, a10 = 0.f, a11 = 0.f;
            float a12 = 0.f, a13 = 0.f, a14 = 0.f, a15 = 0.f;
            int i = beg;
            for (; i + 8 <= end; i += 8) {
                int s0 = csr_src[i + 0], s1 = csr_src[i + 1];
                int s2 = csr_src[i + 2], s3 = csr_src[i + 3];
                int s4 = csr_src[i + 4], s5 = csr_src[i + 5];
                int s6 = csr_src[i + 6], s7 = csr_src[i + 7];
                GATHER(0) GATHER(1) GATHER(2) GATHER(3)
                GATHER(4) GATHER(5) GATHER(6) GATHER(7)
                ACCUM(A0, B0) ACCUM(A1, B1) ACCUM(A2, B2) ACCUM(A3, B3)
                ACCUM(A4, B4) ACCUM(A5, B5) ACCUM(A6, B6) ACCUM(A7, B7)
            }
            if (i < end) {   // masked batch-8 tail: clamp idx, zero invalid slots
                const int e1 = end - 1;
                int s0 = csr_src[i + 0];
                int s1 = csr_src[(i + 1 <= e1) ? i + 1 : e1];
                int s2 = csr_src[(i + 2 <= e1) ? i + 2 : e1];
                int s3 = csr_src[(i + 3 <= e1) ? i + 3 : e1];
                int s4 = csr_src[(i + 4 <= e1) ? i + 4 : e1];
                int s5 = csr_src[(i + 5 <= e1) ? i + 5 : e1];
                int s6 = csr_src[(i + 6 <= e1) ? i + 6 : e1];
                int s7 = csr_src[(i + 7 <= e1) ? i + 7 : e1];
                GATHER(0) GATHER(1) GATHER(2) GATHER(3)
                GATHER(4) GATHER(5) GATHER(6) GATHER(7)
                const uint4 z = {0, 0, 0, 0};
                if (i + 1 > e1) { A1 = z; B1 = z; }
                if (i + 2 > e1) { A2 = z; B2 = z; }
                if (i + 3 > e1) { A3 = z; B3 = z; }
                if (i + 4 > e1) { A4 = z; B4 = z; }
                if (i + 5 > e1) { A5 = z; B5 = z; }
                if (i + 6 > e1) { A6 = z; B6 = z; }
                if (i + 7 > e1) { A7 = z; B7 = z; }
                ACCUM(A0, B0) ACCUM(A1, B1) ACCUM(A2, B2) ACCUM(A3, B3)
                ACCUM(A4, B4) ACCUM(A5, B5) ACCUM(A6, B6) ACCUM(A7, B7)
            }
            float inv = (end > beg) ? 1.0f / (float)(end - beg) : 0.f;
            o0.x = (uint)f2bf(a0 * inv)  | ((uint)f2bf(a1 * inv) << 16);
            o0.y = (uint)f2bf(a2 * inv)  | ((uint)f2bf(a3 * inv) << 16);
            o0.z = (uint)f2bf(a4 * inv)  | ((uint)f2bf(a5 * inv) << 16);
            o0.w = (uint)f2bf(a6 * inv)  | ((uint)f2bf(a7 * inv) << 16);
            o1.x = (uint)f2bf(a8 * inv)  | ((uint)f2bf(a9 * inv) << 16);
            o1.y = (uint)f2bf(a10 * inv) | ((uint)f2bf(a11 * inv) << 16);
            o1.z = (uint)f2bf(a12 * inv) | ((uint)f2bf(a13 * inv) << 16);
            o1.w = (uint)f2bf(a14 * inv) | ((uint)f2bf(a15 * inv) << 16);
        }
        *(uint4*)&sA[g][q * 16] = o0;
        *(uint4*)&sA[g][q * 16 + 8] = o1;
    }
    // no barrier: sA rows are wave-private (wave w wrote rows 16w..16w+15)

    // ---- MFMA: wave w owns rows r0..r0+15; B-fragments straight from global
    const int quad = lane >> 4, lr = lane & 15;
    const int r0 = wave * 16;
    const int grow = row0 + r0 + lr;
    const float alpha = alpha_p[0];

    bf16x8 hf[2], af[2];
#pragma unroll
    for (int ks = 0; ks < 2; ++ks) {
        int k0 = ks * 32 + quad * 8;
        uint4 hv = {0, 0, 0, 0};
        if (grow < N_NODES) hv = *(const uint4*)&hin[(size_t)grow * HID + k0];
        hf[ks] = __builtin_bit_cast(bf16x8, hv);
        uint4 av = *(const uint4*)&sA[r0 + lr][k0];
        af[ks] = __builtin_bit_cast(bf16x8, av);
    }

    f32x4 acc[4];
#pragma unroll
    for (int nt = 0; nt < 4; ++nt) {
        f32x4 a = {0.f, 0.f, 0.f, 0.f};
#pragma unroll
        for (int ks = 0; ks < 2; ++ks) {
            int k0 = ks * 32 + quad * 8;
            bf16x8 wr = *(const bf16x8*)&wr_bf[(nt * 16 + lr) * 64 + k0];
            a = __builtin_amdgcn_mfma_f32_16x16x32_bf16(hf[ks], wr, a, 0, 0, 0);
            bf16x8 wl = *(const bf16x8*)&wl_bf[(nt * 16 + lr) * 64 + k0];
            a = __builtin_amdgcn_mfma_f32_16x16x32_bf16(af[ks], wl, a, 0, 0, 0);
        }
        acc[nt] = a;
    }

    if constexpr (!OUTPROJ) {
        // PReLU result -> sA (wave-private rows), then packed uint4 stores
#pragma unroll
        for (int nt = 0; nt < 4; ++nt) {
            int col = nt * 16 + lr;
            float bias = bl[col];
#pragma unroll
            for (int r = 0; r < 4; ++r) {
                int row = r0 + quad * 4 + r;  // C/D: col=lane&15, row=(lane>>4)*4+reg
                float v = acc[nt][r] + bias;
                v = (v >= 0.f) ? v : alpha * v;
                sA[row][col] = f2bf(v);
            }
        }
        ushort* outp = (ushort*)out_p;
        const int lrow = lane >> 3, lch = lane & 7;  // 8 rows x 8 chunks per pass
#pragma unroll
        for (int pass = 0; pass < 2; ++pass) {
            int row = r0 + pass * 8 + lrow;
            int gg2 = row0 + row;
            if (gg2 < N_NODES) {
                uint4 v4 = *(const uint4*)&sA[row][lch * 8];
                *(uint4*)&outp[(size_t)gg2 * HID + lch * 8] = v4;
            }
        }
    } else {
        // h2 (post-PReLU bf16) -> sA (wave-private rows), then @Wout + bout, f32
#pragma unroll
        for (int nt = 0; nt < 4; ++nt) {
            int col = nt * 16 + lr;
            float bias = bl[col];
#pragma unroll
            for (int r = 0; r < 4; ++r) {
                int row = r0 + quad * 4 + r;
                float v = acc[nt][r] + bias;
                v = (v >= 0.f) ? v : alpha * v;
                sA[row][col] = f2bf(v);
            }
        }
        bf16x8 h2f[2];
#pragma unroll
        for (int ks = 0; ks < 2; ++ks) {
            int k0 = ks * 32 + quad * 8;
            uint4 hv = *(const uint4*)&sA[r0 + lr][k0];
            h2f[ks] = __builtin_bit_cast(bf16x8, hv);
        }
        f32x4 acc2[4];
#pragma unroll
        for (int nt = 0; nt < 4; ++nt) {
            f32x4 a = {0.f, 0.f, 0.f, 0.f};
#pragma unroll
            for (int ks = 0; ks < 2; ++ks) {
                int k0 = ks * 32 + quad * 8;
                bf16x8 wo = *(const bf16x8*)&wo_bf[(nt * 16 + lr) * 64 + k0];
                a = __builtin_amdgcn_mfma_f32_16x16x32_bf16(h2f[ks], wo, a, 0, 0, 0);
            }
            acc2[nt] = a;
        }
        float* outp = (float*)out_p;
#pragma unroll
        for (int nt = 0; nt < 4; ++nt) {
            int col = nt * 16 + lr;
            float bias = bo[col];
#pragma unroll
            for (int r = 0; r < 4; ++r) {
                int row = r0 + quad * 4 + r;
                int gg2 = row0 + row;
                if (gg2 < N_NODES)
                    outp[(size_t)gg2 * HID + col] = acc2[nt][r] + bias;
            }
        }
    }
}

extern "C" void kernel_launch(void* const* d_in, const int* in_sizes, int n_in,
                              void* d_out, int out_size, void* d_ws, size_t ws_size,
                              hipStream_t stream) {
    const int*   x    = (const int*)d_in[0];
    const int*   src  = (const int*)d_in[1];
    const int*   dst  = src + N_EDGES;
    const float* emb  = (const float*)d_in[3];
    const float* Wl1  = (const float*)d_in[4];
    const float* bl1  = (const float*)d_in[5];
    const float* Wr1  = (const float*)d_in[6];
    const float* a1   = (const float*)d_in[7];
    const float* Wl2  = (const float*)d_in[8];
    const float* bl2  = (const float*)d_in[9];
    const float* Wr2  = (const float*)d_in[10];
    const float* a2   = (const float*)d_in[11];
    const float* Wout = (const float*)d_in[12];
    const float* bout = (const float*)d_in[13];

    char* ws = (char*)d_ws;
    int*    gh      = (int*)ws;                      // 100,352 (pad 100,416)
    int*    bstart  = (int*)(ws + 101248);           // 832
    int*    rowptr  = (int*)(ws + 102080);           // 400,064
    ushort* wbf     = (ushort*)(ws + 502144);        // 40,960
    uint*   ebuf    = (uint*)(ws + 543104);          // 5,000,000
    int*    csr_src = (int*)(ws + 5543104);          // 5,000,000
    ushort* h0      = (ushort*)(ws + 10543104);      // 12.8 MB
    ushort* h1      = (ushort*)(ws + 23343104);      // 12.8 MB

    ushort* wl1b  = wbf;
    ushort* wr1b  = wbf + 4096;
    ushort* wl2b  = wbf + 8192;
    ushort* wr2b  = wbf + 12288;
    ushort* woutb = wbf + 16384;

    const int layer_blocks = N_NODES / 32;           // 3125 (exact)

    prep<<<EMB_BLOCKS + NBLOCK + 5, 256, 0, stream>>>(
        x, emb, h0, dst, gh, Wl1, Wr1, Wl2, Wr2, Wout, wbf);
    p3_scatter<<<NBLOCK, 256, 0, stream>>>(src, dst, gh, bstart, ebuf);
    p4_csr<<<NB, 256, 0, stream>>>(ebuf, bstart, rowptr, csr_src);

    layer_fused<false><<<layer_blocks, 128, 0, stream>>>(
        rowptr, csr_src, h0, wl1b, bl1, wr1b, a1, wr1b, bl1, h1);
    layer_fused<true><<<layer_blocks, 128, 0, stream>>>(
        rowptr, csr_src, h1, wl2b, bl2, wr2b, a2, woutb, bout, d_out);
}

// Round 9
// 215.368 us; speedup vs baseline: 5.0885x; 1.0908x over previous
//
#include <hip/hip_runtime.h>
#include <hip/hip_bf16.h>

#define N_NODES 100000
#define N_EDGES 1250000
#define HID 64
#define LDSS 72       // LDS row stride in bf16 elems: 64 + 8 pad (144 B rows)
#define NB 196        // buckets of 512 node-ids: (100000+511)/512
#define NBLOCK 128    // edge-slice blocks for hist/P3
#define EMB_BLOCKS 6250  // N_NODES*16/256 exactly

typedef __bf16 bf16x8 __attribute__((ext_vector_type(8)));
typedef float  f32x4  __attribute__((ext_vector_type(4)));

__device__ __forceinline__ float bflo(uint u) {   // low bf16 of packed uint -> f32
    union { unsigned int i; float f; } v; v.i = u << 16; return v.f;
}
__device__ __forceinline__ float bfhi(uint u) {   // high bf16 -> f32
    union { unsigned int i; float f; } v; v.i = u & 0xFFFF0000u; return v.f;
}
__device__ __forceinline__ ushort f2bf(float f) {
    union { float f; unsigned int i; } v; v.f = f;
    unsigned int x = v.i;
    return (ushort)((x + 0x7fffu + ((x >> 16) & 1u)) >> 16);  // RNE
}

// Edge histogram into 196 coarse buckets (dst>>9), per-slice counts to gh.
__global__ __launch_bounds__(256) void hist_k(const int* __restrict__ dst,
                                              int* __restrict__ gh) {
    __shared__ int hist[NB];
    const int tid = threadIdx.x;
    for (int i = tid; i < NB; i += 256) hist[i] = 0;
    __syncthreads();
    const int4* d4 = (const int4*)dst;                // N_EDGES % 4 == 0
    for (int e = blockIdx.x * 256 + tid; e < N_EDGES / 4; e += NBLOCK * 256) {
        int4 v = d4[e];
        atomicAdd(&hist[v.x >> 9], 1);
        atomicAdd(&hist[v.y >> 9], 1);
        atomicAdd(&hist[v.z >> 9], 1);
        atomicAdd(&hist[v.w >> 9], 1);
    }
    __syncthreads();
    for (int i = tid; i < NB; i += 256) gh[blockIdx.x * NB + i] = hist[i];
}

// Fused: blocks [0,128) p3-scatter (needs gh), [128,6378) embed-gather,
// [6378,6383) weight convert. embed/wcvt are independent of p3 -> overlap;
// p3 blocks dispatched first so p4's dependency clears earliest.
__global__ __launch_bounds__(256) void work2(const int* __restrict__ x,
                                             const float* __restrict__ emb,
                                             ushort* __restrict__ h0,
                                             const int* __restrict__ src,
                                             const int* __restrict__ dst,
                                             const int* __restrict__ gh,
                                             int* __restrict__ bstart,
                                             uint* __restrict__ ebuf,
                                             const float* __restrict__ Wl1,
                                             const float* __restrict__ Wr1,
                                             const float* __restrict__ Wl2,
                                             const float* __restrict__ Wr2,
                                             const float* __restrict__ Wout,
                                             ushort* __restrict__ wbf) {
    const int b = blockIdx.x;
    const int tid = threadIdx.x;
    if (b < NBLOCK) {
        // ---- p3 scatter: per-block recompute of column-prefix + bucket scan
        __shared__ int base[NB];
        __shared__ int run[NB];
        __shared__ int wsum[4];
        const int lane = tid & 63, wave = tid >> 6;
        int myTot = 0, myPre = 0;
        if (tid < NB) {
#pragma unroll 8
            for (int bb = 0; bb < NBLOCK; ++bb) {
                int c = gh[bb * NB + tid];
                if (bb == b) myPre = myTot;
                myTot += c;
            }
        }
        int x2 = myTot;
#pragma unroll
        for (int d = 1; d < 64; d <<= 1) {
            int y = __shfl_up(x2, d, 64);
            if (lane >= d) x2 += y;
        }
        if (lane == 63) wsum[wave] = x2;
        __syncthreads();
        if (wave == 0) {
            int s = (lane < 4) ? wsum[lane] : 0;
#pragma unroll
            for (int d = 1; d < 4; d <<= 1) {
                int y = __shfl_up(s, d, 64);
                if (lane >= d) s += y;
            }
            if (lane < 4) wsum[lane] = s;
        }
        __syncthreads();
        int waveoff = (wave == 0) ? 0 : wsum[wave - 1];
        int excl = waveoff + (x2 - myTot);
        if (tid < NB) {
            base[tid] = excl + myPre;
            run[tid] = 0;
            if (b == 0) bstart[tid] = excl;
        }
        if (b == 0 && tid == 0) bstart[NB] = N_EDGES;
        __syncthreads();
        const int4* s4 = (const int4*)src;
        const int4* d4 = (const int4*)dst;
        for (int e = b * 256 + tid; e < N_EDGES / 4; e += NBLOCK * 256) {
            int4 dv = d4[e];
            int4 sv = s4[e];
            int b0 = dv.x >> 9;
            int r0 = atomicAdd(&run[b0], 1);
            ebuf[base[b0] + r0] = ((uint)(dv.x & 511) << 17) | (uint)sv.x;
            int b1 = dv.y >> 9;
            int r1 = atomicAdd(&run[b1], 1);
            ebuf[base[b1] + r1] = ((uint)(dv.y & 511) << 17) | (uint)sv.y;
            int b2 = dv.z >> 9;
            int r2 = atomicAdd(&run[b2], 1);
            ebuf[base[b2] + r2] = ((uint)(dv.z & 511) << 17) | (uint)sv.z;
            int b3 = dv.w >> 9;
            int r3 = atomicAdd(&run[b3], 1);
            ebuf[base[b3] + r3] = ((uint)(dv.w & 511) << 17) | (uint)sv.w;
        }
    } else if (b < NBLOCK + EMB_BLOCKS) {
        // ---- embed gather: h0[i][:] = bf16(emb[x[i]][:])
        int t = (b - NBLOCK) * 256 + tid;
        int row = t >> 4, c = t & 15;
        int idx = x[row];
        float4 v = ((const float4*)(emb + (size_t)idx * HID))[c];
        ushort4 w;
        w.x = f2bf(v.x); w.y = f2bf(v.y); w.z = f2bf(v.z); w.w = f2bf(v.w);
        ((ushort4*)(h0 + (size_t)row * HID))[c] = w;
    } else {
        const int wb = b - NBLOCK - EMB_BLOCKS;
        const float* W = (wb == 0) ? Wl1 : (wb == 1) ? Wr1 :
                         (wb == 2) ? Wl2 : (wb == 3) ? Wr2 : Wout;
        ushort* o = wbf + wb * 4096;
        for (int idx = tid; idx < 4096; idx += 256) {
            int k = idx >> 6, n = idx & 63;
            o[n * 64 + k] = f2bf(W[idx]);   // wbf[m][n*64+k] = bf16(W[k][n])
        }
    }
}

__global__ __launch_bounds__(256) void p4_csr(const uint* __restrict__ ebuf,
                                              const int* __restrict__ bstart,
                                              int* __restrict__ rowptr,
                                              int* __restrict__ csr_src) {
    __shared__ int hist[512], hoff[512], run[512];
    __shared__ int wsum[4];
    const int v = blockIdx.x;
    const int tid = threadIdx.x, lane = tid & 63, wave = tid >> 6;
    const int node0 = v << 9;
    const int nn = min(512, N_NODES - node0);
    const int beg = bstart[v], end = bstart[v + 1];

    for (int i = tid; i < 512; i += 256) { hist[i] = 0; run[i] = 0; }
    __syncthreads();
    for (int e = beg + tid; e < end; e += 256)
        atomicAdd(&hist[ebuf[e] >> 17], 1);
    __syncthreads();
    int h0 = hist[2 * tid], h1 = hist[2 * tid + 1];
    int s = h0 + h1;
    int x = s;
#pragma unroll
    for (int d = 1; d < 64; d <<= 1) {
        int y = __shfl_up(x, d, 64);
        if (lane >= d) x += y;
    }
    if (lane == 63) wsum[wave] = x;
    __syncthreads();
    if (wave == 0) {
        int s2 = (lane < 4) ? wsum[lane] : 0;
#pragma unroll
        for (int d = 1; d < 4; d <<= 1) {
            int y = __shfl_up(s2, d, 64);
            if (lane >= d) s2 += y;
        }
        if (lane < 4) wsum[lane] = s2;
    }
    __syncthreads();
    int waveoff = (wave == 0) ? 0 : wsum[wave - 1];
    int excl = waveoff + (x - s);
    hoff[2 * tid] = excl;
    hoff[2 * tid + 1] = excl + h0;
    __syncthreads();
    for (int j = tid; j < nn; j += 256) rowptr[node0 + j] = beg + hoff[j];
    if (v == NB - 1 && tid == 0) rowptr[N_NODES] = N_EDGES;
    for (int e = beg + tid; e < end; e += 256) {
        uint p = ebuf[e];
        int dl = p >> 17;
        int r = atomicAdd(&run[dl], 1);
        csr_src[beg + hoff[dl] + r] = (int)(p & 0x1FFFFu);
    }
}

#define ACCUM(wa, wb)                                                      \
    a0 += bflo(wa.x); a1 += bfhi(wa.x); a2 += bflo(wa.y); a3 += bfhi(wa.y); \
    a4 += bflo(wa.z); a5 += bfhi(wa.z); a6 += bflo(wa.w); a7 += bfhi(wa.w); \
    a8 += bflo(wb.x); a9 += bfhi(wb.x); a10 += bflo(wb.y); a11 += bfhi(wb.y); \
    a12 += bflo(wb.z); a13 += bfhi(wb.z); a14 += bflo(wb.w); a15 += bfhi(wb.w);

#define GATHER(j)                                                          \
    const uint4* p##j = (const uint4*)&hin[(size_t)s##j * HID + q * 16];   \
    uint4 A##j = p##j[0], B##j = p##j[1];

// Fused layer: 8-lane/node half-split aggregation + MFMA GEMM.
//  - 256 threads, 32 nodes/block (3125 blocks exact). Node nl = tid>>3.
//  - lanes h=0 take edges [beg,mid), h=1 take [mid,end): half-degree ~6.25
//    -> the TYPICAL node is ONE masked batch per half (vs 2-3 serial batches
//    at 4-lane), per-node in-flight loads double, divergence tail halves.
//  - combine halves with 16x __shfl_xor(.,4); h=0 lanes write sA.
//  - one __syncthreads, then waves 0-1 run the proven MFMA/epilogue for
//    rows 0-31; waves 2-3 retire (MFMA phase is a small fraction).
//  - weights + hin A-fragments read directly from global (L2-hot).
template <bool OUTPROJ>
__global__ __launch_bounds__(256, 4) void layer_fused(
    const int* __restrict__ rowptr, const int* __restrict__ csr_src,
    const ushort* __restrict__ hin,
    const ushort* __restrict__ wl_bf, const float* __restrict__ bl,
    const ushort* __restrict__ wr_bf, const float* __restrict__ alpha_p,
    const ushort* __restrict__ wo_bf, const float* __restrict__ bo,
    void* __restrict__ out_p) {
    __shared__ __align__(16) ushort sA[32][LDSS];      // 4608 B

    const int tid = threadIdx.x;
    const int row0 = blockIdx.x * 32;
    const int wave = tid >> 6, lane = tid & 63;

    // ---- aggregation: 8 lanes/node; q = 16-dim piece, hh = edge half
    const int nl = tid >> 3, hh = (tid >> 2) & 1, q = tid & 3;
    {
        const int node = row0 + nl;                    // < N_NODES always
        const int beg = rowptr[node], end = rowptr[node + 1];
        const int d = end - beg;
        const int mid = beg + ((d + 1) >> 1);
        const int hbeg = hh ? mid : beg;
        const int hend = hh ? end : mid;
        float a0 = 0.f, a1 = 0.f, a2 = 0.f, a3 = 0.f;
        float a4 = 0.f, a5 = 0.f, a6 = 0.f, a7 = 0.f;
        float a8 = 0.f, a9 = 0.f, a10 = 0.f, a11 = 0.f;
        float a12 = 0.f, a13 = 0.f, a14 = 0.f, a15 = 0.f;
        int i = hbeg;
        for (; i + 8 <= hend; i += 8) {
            int s0 = csr_src[i + 0], s1 = csr_src[i + 1];
            int s2 = csr_src[i + 2], s3 = csr_src[i + 3];
            int s4 = csr_src[i + 4], s5 = csr_src[i + 5];
            int s6 = csr_src[i + 6], s7 = csr_src[i + 7];
            GATHER(0) GATHER(1) GATHER(2) GATHER(3)
            GATHER(4) GATHER(5) GATHER(6) GATHER(7)
            ACCUM(A0, B0) ACCUM(A1, B1) ACCUM(A2, B2) ACCUM(A3, B3)
            ACCUM(A4, B4) ACCUM(A5, B5) ACCUM(A6, B6) ACCUM(A7, B7)
        }
        if (i < hend) {     // masked batch-8 tail: clamp idx, zero invalid
            const int e1 = hend - 1;
            int s0 = csr_src[i + 0];
            int s1 = csr_src[(i + 1 <= e1) ? i + 1 : e1];
            int s2 = csr_src[(i + 2 <= e1) ? i + 2 : e1];
            int s3 = csr_src[(i + 3 <= e1) ? i + 3 : e1];
            int s4 = csr_src[(i + 4 <= e1) ? i + 4 : e1];
            int s5 = csr_src[(i + 5 <= e1) ? i + 5 : e1];
            int s6 = csr_src[(i + 6 <= e1) ? i + 6 : e1];
            int s7 = csr_src[(i + 7 <= e1) ? i + 7 : e1];
            GATHER(0) GATHER(1) GATHER(2) GATHER(3)
            GATHER(4) GATHER(5) GATHER(6) GATHER(7)
            const uint4 z = {0, 0, 0, 0};
            if (i + 1 > e1) { A1 = z; B1 = z; }
            if (i + 2 > e1) { A2 = z; B2 = z; }
            if (i + 3 > e1) { A3 = z; B3 = z; }
            if (i + 4 > e1) { A4 = z; B4 = z; }
            if (i + 5 > e1) { A5 = z; B5 = z; }
            if (i + 6 > e1) { A6 = z; B6 = z; }
            if (i + 7 > e1) { A7 = z; B7 = z; }
            ACCUM(A0, B0) ACCUM(A1, B1) ACCUM(A2, B2) ACCUM(A3, B3)
            ACCUM(A4, B4) ACCUM(A5, B5) ACCUM(A6, B6) ACCUM(A7, B7)
        }
        // combine the two halves (lanes differ in tid bit 2)
        a0 += __shfl_xor(a0, 4, 64);   a1 += __shfl_xor(a1, 4, 64);
        a2 += __shfl_xor(a2, 4, 64);   a3 += __shfl_xor(a3, 4, 64);
        a4 += __shfl_xor(a4, 4, 64);   a5 += __shfl_xor(a5, 4, 64);
        a6 += __shfl_xor(a6, 4, 64);   a7 += __shfl_xor(a7, 4, 64);
        a8 += __shfl_xor(a8, 4, 64);   a9 += __shfl_xor(a9, 4, 64);
        a10 += __shfl_xor(a10, 4, 64); a11 += __shfl_xor(a11, 4, 64);
        a12 += __shfl_xor(a12, 4, 64); a13 += __shfl_xor(a13, 4, 64);
        a14 += __shfl_xor(a14, 4, 64); a15 += __shfl_xor(a15, 4, 64);
        if (hh == 0) {
            float inv = (d > 0) ? 1.0f / (float)d : 0.f;
            uint4 o0, o1;
            o0.x = (uint)f2bf(a0 * inv)  | ((uint)f2bf(a1 * inv) << 16);
            o0.y = (uint)f2bf(a2 * inv)  | ((uint)f2bf(a3 * inv) << 16);
            o0.z = (uint)f2bf(a4 * inv)  | ((uint)f2bf(a5 * inv) << 16);
            o0.w = (uint)f2bf(a6 * inv)  | ((uint)f2bf(a7 * inv) << 16);
            o1.x = (uint)f2bf(a8 * inv)  | ((uint)f2bf(a9 * inv) << 16);
            o1.y = (uint)f2bf(a10 * inv) | ((uint)f2bf(a11 * inv) << 16);
            o1.z = (uint)f2bf(a12 * inv) | ((uint)f2bf(a13 * inv) << 16);
            o1.w = (uint)f2bf(a14 * inv) | ((uint)f2bf(a15 * inv) << 16);
            *(uint4*)&sA[nl][q * 16] = o0;
            *(uint4*)&sA[nl][q * 16 + 8] = o1;
        }
    }
    __syncthreads();
    if (wave >= 2) return;          // waves 2-3 done (no further barriers)

    // ---- MFMA: waves 0-1 own rows 0-31; B-fragments straight from global
    const int quad = lane >> 4, lr = lane & 15;
    const int r0 = wave * 16;
    const int grow = row0 + r0 + lr;
    const float alpha = alpha_p[0];

    bf16x8 hf[2], af[2];
#pragma unroll
    for (int ks = 0; ks < 2; ++ks) {
        int k0 = ks * 32 + quad * 8;
        uint4 hv = *(const uint4*)&hin[(size_t)grow * HID + k0];
        hf[ks] = __builtin_bit_cast(bf16x8, hv);
        uint4 av = *(const uint4*)&sA[r0 + lr][k0];
        af[ks] = __builtin_bit_cast(bf16x8, av);
    }

    f32x4 acc[4];
#pragma unroll
    for (int nt = 0; nt < 4; ++nt) {
        f32x4 a = {0.f, 0.f, 0.f, 0.f};
#pragma unroll
        for (int ks = 0; ks < 2; ++ks) {
            int k0 = ks * 32 + quad * 8;
            bf16x8 wr = *(const bf16x8*)&wr_bf[(nt * 16 + lr) * 64 + k0];
            a = __builtin_amdgcn_mfma_f32_16x16x32_bf16(hf[ks], wr, a, 0, 0, 0);
            bf16x8 wl = *(const bf16x8*)&wl_bf[(nt * 16 + lr) * 64 + k0];
            a = __builtin_amdgcn_mfma_f32_16x16x32_bf16(af[ks], wl, a, 0, 0, 0);
        }
        acc[nt] = a;
    }

    if constexpr (!OUTPROJ) {
        // PReLU result -> sA (wave-private rows), then packed uint4 stores
#pragma unroll
        for (int nt = 0; nt < 4; ++nt) {
            int col = nt * 16 + lr;
            float bias = bl[col];
#pragma unroll
            for (int r = 0; r < 4; ++r) {
                int row = r0 + quad * 4 + r;  // C/D: col=lane&15, row=(lane>>4)*4+reg
                float v = acc[nt][r] + bias;
                v = (v >= 0.f) ? v : alpha * v;
                sA[row][col] = f2bf(v);
            }
        }
        ushort* outp = (ushort*)out_p;
        const int lrow = lane >> 3, lch = lane & 7;  // 8 rows x 8 chunks per pass
#pragma unroll
        for (int pass = 0; pass < 2; ++pass) {
            int row = r0 + pass * 8 + lrow;
            int gg2 = row0 + row;
            uint4 v4 = *(const uint4*)&sA[row][lch * 8];
            *(uint4*)&outp[(size_t)gg2 * HID + lch * 8] = v4;
        }
    } else {
        // h2 (post-PReLU bf16) -> sA (wave-private rows), then @Wout + bout, f32
#pragma unroll
        for (int nt = 0; nt < 4; ++nt) {
            int col = nt * 16 + lr;
            float bias = bl[col];
#pragma unroll
            for (int r = 0; r < 4; ++r) {
                int row = r0 + quad * 4 + r;
                float v = acc[nt][r] + bias;
                v = (v >= 0.f) ? v : alpha * v;
                sA[row][col] = f2bf(v);
            }
        }
        bf16x8 h2f[2];
#pragma unroll
        for (int ks = 0; ks < 2; ++ks) {
            int k0 = ks * 32 + quad * 8;
            uint4 hv = *(const uint4*)&sA[r0 + lr][k0];
            h2f[ks] = __builtin_bit_cast(bf16x8, hv);
        }
        f32x4 acc2[4];
#pragma unroll
        for (int nt = 0; nt < 4; ++nt) {
            f32x4 a = {0.f, 0.f, 0.f, 0.f};
#pragma unroll
            for (int ks = 0; ks < 2; ++ks) {
                int k0 = ks * 32 + quad * 8;
                bf16x8 wo = *(const bf16x8*)&wo_bf[(nt * 16 + lr) * 64 + k0];
                a = __builtin_amdgcn_mfma_f32_16x16x32_bf16(h2f[ks], wo, a, 0, 0, 0);
            }
            acc2[nt] = a;
        }
        float* outp = (float*)out_p;
#pragma unroll
        for (int nt = 0; nt < 4; ++nt) {
            int col = nt * 16 + lr;
            float bias = bo[col];
#pragma unroll
            for (int r = 0; r < 4; ++r) {
                int row = r0 + quad * 4 + r;
                int gg2 = row0 + row;
                outp[(size_t)gg2 * HID + col] = acc2[nt][r] + bias;
            }
        }
    }
}

extern "C" void kernel_launch(void* const* d_in, const int* in_sizes, int n_in,
                              void* d_out, int out_size, void* d_ws, size_t ws_size,
                              hipStream_t stream) {
    const int*   x    = (const int*)d_in[0];
    const int*   src  = (const int*)d_in[1];
    const int*   dst  = src + N_EDGES;
    const float* emb  = (const float*)d_in[3];
    const float* Wl1  = (const float*)d_in[4];
    const float* bl1  = (const float*)d_in[5];
    const float* Wr1  = (const float*)d_in[6];
    const float* a1   = (const float*)d_in[7];
    const float* Wl2  = (const float*)d_in[8];
    const float* bl2  = (const float*)d_in[9];
    const float* Wr2  = (const float*)d_in[10];
    const float* a2   = (const float*)d_in[11];
    const float* Wout = (const float*)d_in[12];
    const float* bout = (const float*)d_in[13];

    char* ws = (char*)d_ws;
    int*    gh      = (int*)ws;                      // 100,352 (pad 100,416)
    int*    bstart  = (int*)(ws + 101248);           // 832
    int*    rowptr  = (int*)(ws + 102080);           // 400,064
    ushort* wbf     = (ushort*)(ws + 502144);        // 40,960
    uint*   ebuf    = (uint*)(ws + 543104);          // 5,000,000
    int*    csr_src = (int*)(ws + 5543104);          // 5,000,000
    ushort* h0      = (ushort*)(ws + 10543104);      // 12.8 MB
    ushort* h1      = (ushort*)(ws + 23343104);      // 12.8 MB

    ushort* wl1b  = wbf;
    ushort* wr1b  = wbf + 4096;
    ushort* wl2b  = wbf + 8192;
    ushort* wr2b  = wbf + 12288;
    ushort* woutb = wbf + 16384;

    const int layer_blocks = N_NODES / 32;           // 3125 (exact)

    hist_k<<<NBLOCK, 256, 0, stream>>>(dst, gh);
    work2<<<NBLOCK + EMB_BLOCKS + 5, 256, 0, stream>>>(
        x, emb, h0, src, dst, gh, bstart, ebuf, Wl1, Wr1, Wl2, Wr2, Wout, wbf);
    p4_csr<<<NB, 256, 0, stream>>>(ebuf, bstart, rowptr, csr_src);

    layer_fused<false><<<layer_blocks, 256, 0, stream>>>(
        rowptr, csr_src, h0, wl1b, bl1, wr1b, a1, wr1b, bl1, h1);
    layer_fused<true><<<layer_blocks, 256, 0, stream>>>(
        rowptr, csr_src, h1, wl2b, bl2, wr2b, a2, woutb, bout, d_out);
}